// Round 1
// baseline (240.289 us; speedup 1.0000x reference)
//
#include <hip/hip_runtime.h>
#include <math.h>

#define NK 1024          // number of knots
#define NB 4096          // acceleration buckets

// ws float layout:
//   [0 .. 1024]   sorted xp (1025 incl. +inf sentinel)
//   [1025]        lo   (min knot x)
//   [1026]        scale (NB / range)
//   [1027]        pad
//   [1028 .. 5123] quads: 1024 x float4 {x[i], y[i], x[i+1], y[i+1]}  (16B aligned)
//   [5124 .. ]    table: 4096 ushort (8192 bytes)
#define WS_QUAD_OFF 1028
#define WS_TAB_OFF  (1028 + 4096)

// Monotone bucket map — MUST be bit-identical between setup (knots) and main
// (queries): correctness of table[b] as a lower bound needs
// xp[i] >= x  ==>  bucket(xp[i]) >= bucket(x). __fsub_rn/__fmul_rn forbid
// contraction; trunc-toward-zero and clamp are monotone.
__device__ __forceinline__ int bucket_of(float x, float lo, float scale) {
    float t = __fmul_rn(__fsub_rn(x, lo), scale);
    int b = (int)t;
    b = b < 0 ? 0 : b;
    b = b > (NB - 1) ? (NB - 1) : b;
    return b;
}

__global__ __launch_bounds__(1024) void setup_kernel(
        const float* __restrict__ xp_in, const float* __restrict__ yp_in,
        float* __restrict__ wsf)
{
    __shared__ float2 kv[NK];
    __shared__ float2 kv2[NK];
    __shared__ int    hist[NB];
    __shared__ int    starts[NB];
    __shared__ int    iscan[NK];
    __shared__ float  red[NK];
    __shared__ int    flag;
    __shared__ float  s_lo, s_scale;

    const int t = threadIdx.x;
    float xv = xp_in[t];
    kv[t] = make_float2(xv, yp_in[t]);

    // min/max reduce over knot x
    red[t] = xv; __syncthreads();
    for (int s = 512; s > 0; s >>= 1) {
        if (t < s) red[t] = fminf(red[t], red[t + s]);
        __syncthreads();
    }
    if (t == 0) s_lo = red[0];
    __syncthreads();
    red[t] = xv; __syncthreads();
    for (int s = 512; s > 0; s >>= 1) {
        if (t < s) red[t] = fmaxf(red[t], red[t + s]);
        __syncthreads();
    }
    if (t == 0) {
        float range = red[0] - s_lo;
        s_scale = (range > 0.0f) ? ((float)NB / range) : 0.0f;
    }
    __syncthreads();
    const float lo = s_lo, scale = s_scale;

    // histogram of knot buckets
    for (int i = t; i < NB; i += NK) hist[i] = 0;
    __syncthreads();
    const int bt = bucket_of(xv, lo, scale);
    atomicAdd(&hist[bt], 1);
    __syncthreads();

    // exclusive prefix sum over 4096 buckets (two-level; thread t owns 4 slots)
    int c0 = hist[4 * t], c1 = hist[4 * t + 1], c2 = hist[4 * t + 2], c3 = hist[4 * t + 3];
    int tot = c0 + c1 + c2 + c3;
    iscan[t] = tot; __syncthreads();
    for (int off = 1; off < NK; off <<= 1) {
        int v = (t >= off) ? iscan[t - off] : 0;
        __syncthreads();
        iscan[t] += v;
        __syncthreads();
    }
    int excl = iscan[t] - tot;
    starts[4 * t]     = excl;
    starts[4 * t + 1] = excl + c0;
    starts[4 * t + 2] = excl + c0 + c1;
    starts[4 * t + 3] = excl + c0 + c1 + c2;
    __syncthreads();

    // scatter into bucket order
    for (int i = t; i < NB; i += NK) hist[i] = 0;
    __syncthreads();
    int pos = starts[bt] + atomicAdd(&hist[bt], 1);
    kv2[pos] = kv[t];
    __syncthreads();

    // odd-even transposition cleanup until fully sorted (tiny displacements)
    for (;;) {
        if (t == 0) flag = 0;
        __syncthreads();
        if (t < NK / 2) {
            int i0 = 2 * t;
            float2 a = kv2[i0], b = kv2[i0 + 1];
            if (a.x > b.x) { kv2[i0] = b; kv2[i0 + 1] = a; flag = 1; }
        }
        __syncthreads();
        if (t < NK / 2 - 1) {
            int i0 = 2 * t + 1;
            float2 a = kv2[i0], b = kv2[i0 + 1];
            if (a.x > b.x) { kv2[i0] = b; kv2[i0 + 1] = a; flag = 1; }
        }
        __syncthreads();
        if (!flag) break;
    }

    // emit: sorted xp (+sentinel), meta, quads, bucket table
    wsf[t] = kv2[t].x;
    if (t == 0) {
        wsf[NK]   = INFINITY;   // sentinel terminates the scan loop
        wsf[1025] = lo;
        wsf[1026] = scale;
    }
    float2 cur = kv2[t];
    float2 nxt = kv2[(t == NK - 1) ? (NK - 1) : (t + 1)];
    float4* qg = (float4*)(wsf + WS_QUAD_OFF);
    qg[t] = make_float4(cur.x, cur.y, nxt.x, nxt.y);
    unsigned short* tg = (unsigned short*)(wsf + WS_TAB_OFF);
    tg[4 * t]     = (unsigned short)starts[4 * t];
    tg[4 * t + 1] = (unsigned short)starts[4 * t + 1];
    tg[4 * t + 2] = (unsigned short)starts[4 * t + 2];
    tg[4 * t + 3] = (unsigned short)starts[4 * t + 3];
}

__device__ __forceinline__ float interp_one(
        float x, const float* __restrict__ sxp, const float4* __restrict__ quads,
        const unsigned short* __restrict__ table,
        float lo, float scale, float xp0, float xpN, float yp0, float ypN)
{
    int b = bucket_of(x, lo, scale);
    int j = table[b];                 // lower bound on searchsorted index
    while (sxp[j] < x) ++j;           // expected ~0.1 iters; inf sentinel stops
    int hi = j < 1 ? 1 : (j > NK - 1 ? NK - 1 : j);
    float4 qd = quads[hi - 1];        // {x1, y1, x2, y2}
    float r = __builtin_amdgcn_rcpf(qd.z - qd.x);
    float res = qd.y + (x - qd.x) * (qd.w - qd.y) * r;
    res = (x <= xp0) ? yp0 : res;     // idx == 0
    res = (x >  xpN) ? ypN : res;     // idx == n
    return res;
}

__global__ __launch_bounds__(256, 4) void interp_kernel(
        const float4* __restrict__ xq, float4* __restrict__ out,
        const float* __restrict__ wsf, int n4)
{
    __shared__ float          sxp[NK + 1];
    __shared__ float4         quads[NK];
    __shared__ unsigned short table[NB];

    const int t = threadIdx.x;
    for (int i = t; i < NK + 1; i += 256) sxp[i] = wsf[i];
    const float lo = wsf[1025], scale = wsf[1026];
    const float4* qsrc = (const float4*)(wsf + WS_QUAD_OFF);
    for (int i = t; i < NK; i += 256) quads[i] = qsrc[i];
    const unsigned int* tsrc = (const unsigned int*)(wsf + WS_TAB_OFF);
    unsigned int* tdst = (unsigned int*)table;
    for (int i = t; i < NB / 2; i += 256) tdst[i] = tsrc[i];
    __syncthreads();

    const float xp0 = sxp[0], xpN = sxp[NK - 1];
    const float yp0 = quads[0].y, ypN = quads[NK - 1].y;

    int idx = blockIdx.x * 256 + t;
    const int stride = gridDim.x * 256;
    for (int q = idx; q < n4; q += stride) {
        float4 xv = xq[q];
        float4 r;
        r.x = interp_one(xv.x, sxp, quads, table, lo, scale, xp0, xpN, yp0, ypN);
        r.y = interp_one(xv.y, sxp, quads, table, lo, scale, xp0, xpN, yp0, ypN);
        r.z = interp_one(xv.z, sxp, quads, table, lo, scale, xp0, xpN, yp0, ypN);
        r.w = interp_one(xv.w, sxp, quads, table, lo, scale, xp0, xpN, yp0, ypN);
        out[q] = r;
    }
}

extern "C" void kernel_launch(void* const* d_in, const int* in_sizes, int n_in,
                              void* d_out, int out_size, void* d_ws, size_t ws_size,
                              hipStream_t stream)
{
    const float* x  = (const float*)d_in[0];
    const float* xp = (const float*)d_in[1];
    const float* yp = (const float*)d_in[2];
    float* out = (float*)d_out;
    float* wsf = (float*)d_ws;

    setup_kernel<<<1, 1024, 0, stream>>>(xp, yp, wsf);

    const int n4 = out_size / 4;   // 33,554,432 / 4
    interp_kernel<<<1280, 256, 0, stream>>>((const float4*)x, (float4*)out, wsf, n4);
}